// Round 2
// baseline (2223.954 us; speedup 1.0000x reference)
//
#include <hip/hip_runtime.h>
#include <stdint.h>

// Problem constants (match reference)
#define SLAB 8192    // SL
#define SUNL 16384   // SU
#define DIMX 1024
#define HID1 2048
#define HID2 512
#define KTRIES 8

// ---------------------------------------------------------------------------
// Threefry2x32 (JAX-compatible, 20 rounds)
// ---------------------------------------------------------------------------
struct U2 { uint32_t x, y; };

__device__ __forceinline__ U2 threefry(uint32_t k0, uint32_t k1, uint32_t x0, uint32_t x1) {
  uint32_t ks2 = k0 ^ k1 ^ 0x1BD11BDAu;
  x0 += k0; x1 += k1;
#define TF_R(r) { x0 += x1; x1 = (x1 << (r)) | (x1 >> (32 - (r))); x1 ^= x0; }
  TF_R(13) TF_R(15) TF_R(26) TF_R(6)
  x0 += k1; x1 += ks2 + 1u;
  TF_R(17) TF_R(29) TF_R(16) TF_R(24)
  x0 += ks2; x1 += k0 + 2u;
  TF_R(13) TF_R(15) TF_R(26) TF_R(6)
  x0 += k0; x1 += k1 + 3u;
  TF_R(17) TF_R(29) TF_R(16) TF_R(24)
  x0 += k1; x1 += ks2 + 4u;
  TF_R(13) TF_R(15) TF_R(26) TF_R(6)
  x0 += ks2; x1 += k0 + 5u;
#undef TF_R
  return {x0, x1};
}

// ---------------------------------------------------------------------------
// Pair sampling: replicates JAX partitionable-threefry path.
//   key(42) = (0,42)
//   split child j (foldlike)   = threefry(key, (0, j))  -> 64-bit key
//   randint lower-bits key     = child 1 of randint's internal split
//   32-bit draw at flat t      = bits1 ^ bits2 of threefry(k, (0, t))
//     [_threefry_random_bits_partitionable folds the 2x32 output via XOR
//      for bit_width <= 32 — NOT bits2 alone (R0's bug)]
//   span=8192 (pow2) -> randint multiplier = (2^16 % 2^13)^2 % 2^13 = 0,
//   so value = lower_bits & 8191.
// ---------------------------------------------------------------------------
__global__ __launch_bounds__(256) void pairs_kernel(
    const float* __restrict__ y_l, const float* __restrict__ y_u,
    int* __restrict__ ai, int* __restrict__ bi, float* __restrict__ kv)
{
  int r = blockIdx.x * 256 + threadIdx.x;
  if (r >= SUNL) return;

  U2 ka  = threefry(0u, 42u, 0u, 0u);   // split(key)[0]
  U2 kb  = threefry(0u, 42u, 0u, 1u);   // split(key)[1]
  U2 k2a = threefry(ka.x, ka.y, 0u, 1u); // randint(ka) internal split child 1
  U2 k2b = threefry(kb.x, kb.y, 0u, 1u); // randint(kb) internal split child 1

  int iav[KTRIES], ibv[KTRIES];
#pragma unroll
  for (int c = 0; c < KTRIES; ++c) {
    uint32_t t = (uint32_t)(r * KTRIES + c);
    U2 oa = threefry(k2a.x, k2a.y, 0u, t);
    U2 ob = threefry(k2b.x, k2b.y, 0u, t);
    iav[c] = (int)((oa.x ^ oa.y) & (SLAB - 1));   // bits1 ^ bits2
    ibv[c] = (int)((ob.x ^ ob.y) & (SLAB - 1));
  }

  // first = argmax(valid) -> first valid index, 0 if none
  int a = iav[0], b = ibv[0];
#pragma unroll
  for (int c = 0; c < KTRIES; ++c) {
    if (iav[c] != ibv[c] && y_l[iav[c]] != y_l[ibv[c]]) { a = iav[c]; b = ibv[c]; break; }
  }
  float ya = y_l[a], yb = y_l[b];
  float k = (y_u[r] - yb) / (ya - yb);
  ai[r] = a; bi[r] = b; kv[r] = k;
}

// ---------------------------------------------------------------------------
// FP32 tiled GEMM: C[M,N] = act(A[M,K] @ B[K,N] + bias), row-major.
// 64x64 tile, BK=16, 256 threads, 4x4 per thread, float4 global + LDS.
// ---------------------------------------------------------------------------
#define BM 64
#define BN 64
#define BKT 16

__global__ __launch_bounds__(256) void gemm_bias_relu(
    const float* __restrict__ A, const float* __restrict__ B,
    const float* __restrict__ bias, float* __restrict__ C,
    int M, int N, int K, int do_relu)
{
  __shared__ float As[BKT][BM + 4];  // +4 pad: breaks store conflicts, keeps 16B align
  __shared__ float Bs[BKT][BN + 4];

  int tid = threadIdx.x;
  int m0 = blockIdx.y * BM, n0 = blockIdx.x * BN;
  int tx = tid & 15, ty = tid >> 4;

  int am = tid >> 2;           // A tile row 0..63
  int ak = (tid & 3) << 2;     // A tile col 0,4,8,12
  int bk = tid >> 4;           // B tile row 0..15
  int bn4 = (tid & 15) << 2;   // B tile col 0..60

  float acc[4][4] = {};
  const int ntiles = K / BKT;
  for (int t = 0; t < ntiles; ++t) {
    int k0 = t * BKT;
    float4 av = *(const float4*)(A + (size_t)(m0 + am) * K + k0 + ak);
    float4 bv = *(const float4*)(B + (size_t)(k0 + bk) * N + n0 + bn4);
    As[ak + 0][am] = av.x;
    As[ak + 1][am] = av.y;
    As[ak + 2][am] = av.z;
    As[ak + 3][am] = av.w;
    *(float4*)&Bs[bk][bn4] = bv;
    __syncthreads();
#pragma unroll
    for (int kk = 0; kk < BKT; ++kk) {
      float4 a4 = *(const float4*)&As[kk][ty << 2];
      float4 b4 = *(const float4*)&Bs[kk][tx << 2];
      float a[4] = {a4.x, a4.y, a4.z, a4.w};
      float b[4] = {b4.x, b4.y, b4.z, b4.w};
#pragma unroll
      for (int i = 0; i < 4; i++)
#pragma unroll
        for (int j = 0; j < 4; j++)
          acc[i][j] = fmaf(a[i], b[j], acc[i][j]);
    }
    __syncthreads();
  }

  float4 bb = *(const float4*)(bias + n0 + (tx << 2));
  float bias4[4] = {bb.x, bb.y, bb.z, bb.w};
#pragma unroll
  for (int i = 0; i < 4; i++) {
    float4 o;
    float* op = (float*)&o;
#pragma unroll
    for (int j = 0; j < 4; j++) {
      float v = acc[i][j] + bias4[j];
      if (do_relu) v = fmaxf(v, 0.0f);
      op[j] = v;
    }
    *(float4*)(C + (size_t)(m0 + (ty << 2) + i) * N + n0 + (tx << 2)) = o;
  }
}

// ---------------------------------------------------------------------------
// y_hat[r] = dot(feat_l[r], W3) + b3   (one wave per row)
// ---------------------------------------------------------------------------
__global__ __launch_bounds__(256) void yhat_kernel(
    const float* __restrict__ feat_l, const float* __restrict__ W3,
    const float* __restrict__ b3, float* __restrict__ out)
{
  int wave = threadIdx.x >> 6;
  int lane = threadIdx.x & 63;
  int row = blockIdx.x * 4 + wave;
  if (row >= SLAB) return;
  const float* f = feat_l + (size_t)row * HID2;
  float s = 0.f;
#pragma unroll
  for (int j = 0; j < HID2 / 64; ++j) s = fmaf(f[lane + j * 64], W3[lane + j * 64], s);
#pragma unroll
  for (int off = 32; off; off >>= 1) s += __shfl_down(s, off);
  if (lane == 0) out[row] = s + b3[0];
}

// ---------------------------------------------------------------------------
// feat_comb[r] = k[r] * feat_l[a[r]] + (1-k[r]) * feat_l[b[r]]
// 128 threads per row (float4), 2 rows per block.
// ---------------------------------------------------------------------------
__global__ __launch_bounds__(256) void comb_kernel(
    const float* __restrict__ feat_l, const int* __restrict__ ai,
    const int* __restrict__ bi, const float* __restrict__ kv,
    float* __restrict__ out)
{
  int row = blockIdx.x * 2 + (threadIdx.x >> 7);
  int c = (threadIdx.x & 127) << 2;
  float k = kv[row];
  float km1 = 1.0f - k;
  float4 fa = *(const float4*)(feat_l + (size_t)ai[row] * HID2 + c);
  float4 fb = *(const float4*)(feat_l + (size_t)bi[row] * HID2 + c);
  float4 o;
  o.x = k * fa.x + km1 * fb.x;
  o.y = k * fa.y + km1 * fb.y;
  o.z = k * fa.z + km1 * fb.z;
  o.w = k * fa.w + km1 * fb.w;
  *(float4*)(out + (size_t)row * HID2 + c) = o;
}

// ---------------------------------------------------------------------------
extern "C" void kernel_launch(void* const* d_in, const int* in_sizes, int n_in,
                              void* d_out, int out_size, void* d_ws, size_t ws_size,
                              hipStream_t stream)
{
  const float* X_l = (const float*)d_in[0];
  const float* y_l = (const float*)d_in[1];
  const float* X_u = (const float*)d_in[2];
  const float* y_u = (const float*)d_in[3];
  const float* W1  = (const float*)d_in[4];
  const float* b1  = (const float*)d_in[5];
  const float* W2  = (const float*)d_in[6];
  const float* b2  = (const float*)d_in[7];
  const float* W3  = (const float*)d_in[8];
  const float* b3  = (const float*)d_in[9];

  float* out_featu = (float*)d_out;                       // [SU, H2]
  float* out_comb  = out_featu + (size_t)SUNL * HID2;     // [SU, H2]
  float* out_yhat  = out_comb + (size_t)SUNL * HID2;      // [SL, 1]

  // Workspace layout (~218 MB): H_l | H_u | feat_l | ai | bi | kv
  float* H_l    = (float*)d_ws;
  float* H_u    = H_l + (size_t)SLAB * HID1;
  float* feat_l = H_u + (size_t)SUNL * HID1;
  int*   ai     = (int*)(feat_l + (size_t)SLAB * HID2);
  int*   bi     = ai + SUNL;
  float* kv     = (float*)(bi + SUNL);

  dim3 blk(256);

  pairs_kernel<<<dim3(SUNL / 256), blk, 0, stream>>>(y_l, y_u, ai, bi, kv);

  // H_l = relu(X_l @ W1 + b1)
  gemm_bias_relu<<<dim3(HID1 / BN, SLAB / BM), blk, 0, stream>>>(X_l, W1, b1, H_l, SLAB, HID1, DIMX, 1);
  // feat_l = relu(H_l @ W2 + b2)
  gemm_bias_relu<<<dim3(HID2 / BN, SLAB / BM), blk, 0, stream>>>(H_l, W2, b2, feat_l, SLAB, HID2, HID1, 1);
  // H_u = relu(X_u @ W1 + b1)
  gemm_bias_relu<<<dim3(HID1 / BN, SUNL / BM), blk, 0, stream>>>(X_u, W1, b1, H_u, SUNL, HID1, DIMX, 1);
  // feat_u = relu(H_u @ W2 + b2) -> directly into d_out
  gemm_bias_relu<<<dim3(HID2 / BN, SUNL / BM), blk, 0, stream>>>(H_u, W2, b2, out_featu, SUNL, HID2, HID1, 1);

  yhat_kernel<<<dim3(SLAB / 4), blk, 0, stream>>>(feat_l, W3, b3, out_yhat);
  comb_kernel<<<dim3(SUNL / 2), blk, 0, stream>>>(feat_l, ai, bi, kv, out_comb);
}

// Round 3
// 442.916 us; speedup vs baseline: 5.0212x; 5.0212x over previous
//
#include <hip/hip_runtime.h>
#include <stdint.h>

// Problem constants (match reference)
#define SLAB 8192    // SL
#define SUNL 16384   // SU
#define DIMX 1024
#define HID1 2048
#define HID2 512
#define KTRIES 8

typedef __attribute__((ext_vector_type(8))) short bf16x8;  // 8 bf16 = 4 VGPRs
typedef __attribute__((ext_vector_type(4))) float f32x4;

// fp32 -> bf16 round-to-nearest-even (bit-level, no dependence on struct layout)
__device__ __forceinline__ unsigned short f2bf(float f) {
  union { float f; uint32_t u; } c; c.f = f;
  return (unsigned short)((c.u + 0x7fffu + ((c.u >> 16) & 1u)) >> 16);
}

// async global->LDS, 16B per lane; lds dest = wave-uniform base + lane*16
__device__ __forceinline__ void async16(const void* g, void* l) {
  __builtin_amdgcn_global_load_lds(
      (const __attribute__((address_space(1))) unsigned int*)g,
      (__attribute__((address_space(3))) unsigned int*)l,
      16, 0, 0);
}

// ---------------------------------------------------------------------------
// Threefry2x32 (JAX-compatible, 20 rounds)
// ---------------------------------------------------------------------------
struct U2 { uint32_t x, y; };

__device__ __forceinline__ U2 threefry(uint32_t k0, uint32_t k1, uint32_t x0, uint32_t x1) {
  uint32_t ks2 = k0 ^ k1 ^ 0x1BD11BDAu;
  x0 += k0; x1 += k1;
#define TF_R(r) { x0 += x1; x1 = (x1 << (r)) | (x1 >> (32 - (r))); x1 ^= x0; }
  TF_R(13) TF_R(15) TF_R(26) TF_R(6)
  x0 += k1; x1 += ks2 + 1u;
  TF_R(17) TF_R(29) TF_R(16) TF_R(24)
  x0 += ks2; x1 += k0 + 2u;
  TF_R(13) TF_R(15) TF_R(26) TF_R(6)
  x0 += k0; x1 += k1 + 3u;
  TF_R(17) TF_R(29) TF_R(16) TF_R(24)
  x0 += k1; x1 += ks2 + 4u;
  TF_R(13) TF_R(15) TF_R(26) TF_R(6)
  x0 += ks2; x1 += k0 + 5u;
#undef TF_R
  return {x0, x1};
}

// Pair sampling — verified R1 (partitionable threefry; draw = bits1^bits2; &8191)
__global__ __launch_bounds__(256) void pairs_kernel(
    const float* __restrict__ y_l, const float* __restrict__ y_u,
    int* __restrict__ ai, int* __restrict__ bi, float* __restrict__ kv)
{
  int r = blockIdx.x * 256 + threadIdx.x;
  if (r >= SUNL) return;

  U2 ka  = threefry(0u, 42u, 0u, 0u);
  U2 kb  = threefry(0u, 42u, 0u, 1u);
  U2 k2a = threefry(ka.x, ka.y, 0u, 1u);
  U2 k2b = threefry(kb.x, kb.y, 0u, 1u);

  int iav[KTRIES], ibv[KTRIES];
#pragma unroll
  for (int c = 0; c < KTRIES; ++c) {
    uint32_t t = (uint32_t)(r * KTRIES + c);
    U2 oa = threefry(k2a.x, k2a.y, 0u, t);
    U2 ob = threefry(k2b.x, k2b.y, 0u, t);
    iav[c] = (int)((oa.x ^ oa.y) & (SLAB - 1));
    ibv[c] = (int)((ob.x ^ ob.y) & (SLAB - 1));
  }
  int a = iav[0], b = ibv[0];
#pragma unroll
  for (int c = 0; c < KTRIES; ++c) {
    if (iav[c] != ibv[c] && y_l[iav[c]] != y_l[ibv[c]]) { a = iav[c]; b = ibv[c]; break; }
  }
  float ya = y_l[a], yb = y_l[b];
  ai[r] = a; bi[r] = b; kv[r] = (y_u[r] - yb) / (ya - yb);
}

// ---------------------------------------------------------------------------
// cast fp32 -> bf16, 4 elements/thread
// ---------------------------------------------------------------------------
__global__ __launch_bounds__(256) void cast_bf16_kernel(
    const float* __restrict__ X, unsigned short* __restrict__ Xb)
{
  size_t i = (size_t)blockIdx.x * 256 + threadIdx.x;
  float4 v = ((const float4*)X)[i];
  ushort4 o;
  o.x = f2bf(v.x); o.y = f2bf(v.y); o.z = f2bf(v.z); o.w = f2bf(v.w);
  ((ushort4*)Xb)[i] = o;
}

// ---------------------------------------------------------------------------
// transpose + cast: W[K][N] fp32 -> WT[N][K] bf16. 32x32 LDS tile, block (32,8).
// ---------------------------------------------------------------------------
__global__ void transpose_cast_kernel(
    const float* __restrict__ W, unsigned short* __restrict__ WT, int K, int N)
{
  __shared__ float t[32][33];
  int k0 = blockIdx.y * 32, n0 = blockIdx.x * 32;
  int tx = threadIdx.x, ty = threadIdx.y;
#pragma unroll
  for (int i = 0; i < 32; i += 8)
    t[ty + i][tx] = W[(size_t)(k0 + ty + i) * N + n0 + tx];
  __syncthreads();
#pragma unroll
  for (int i = 0; i < 32; i += 8)
    WT[(size_t)(n0 + ty + i) * K + k0 + tx] = f2bf(t[tx][ty + i]);
}

// ---------------------------------------------------------------------------
// bf16 MFMA GEMM (m97 structure): C[M][N] = act(A[M][K] @ Bt[N][K]^T + bias)
// 128x128 tile, BK=32, 256 thr = 4 waves (2x2), each wave 64x64 = 4x4 MFMA tiles.
// Staging: global_load_lds 16B/lane; per wave 2 calls for A + 2 for B.
// Fragments (16x16x32): A/B lane l -> row/col = l&15, k = (l>>4)*8 + 0..7.
// C/D: col = lane&15, row = (lane>>4)*4 + reg   [m89/m91 verified]
// ---------------------------------------------------------------------------
template<int OUT_BF16, int RELU>
__global__ __launch_bounds__(256) void gemm_bt_mfma(
    const unsigned short* __restrict__ A,   // [M][K] bf16
    const unsigned short* __restrict__ Bt,  // [N][K] bf16
    const float* __restrict__ bias,         // [N] fp32
    void* __restrict__ Cout,                // [M][N] bf16 or fp32
    int M, int N, int K)
{
  __shared__ unsigned short As[128 * 32];   // 8 KB
  __shared__ unsigned short Bs[128 * 32];   // 8 KB

  const int tid  = threadIdx.x;
  const int wave = tid >> 6;
  const int lane = tid & 63;
  const int m0 = blockIdx.y * 128;
  const int n0 = blockIdx.x * 128;
  const int wm = (wave >> 1) * 64;   // wave row offset in tile
  const int wn = (wave & 1) * 64;    // wave col offset in tile

  // staging: lane covers tile row (wave*32 + c*16 + lane/4), k-bytes (lane&3)*16
  const int srow = wave * 32 + (lane >> 2);
  const int scol = (lane & 3) * 8;                  // element offset
  const unsigned short* gA = A  + (size_t)(m0 + srow) * K + scol;
  const unsigned short* gB = Bt + (size_t)(n0 + srow) * K + scol;
  unsigned short* lA = As + wave * 32 * 32;         // wave-uniform LDS base
  unsigned short* lB = Bs + wave * 32 * 32;

  const int fr = lane & 15;          // fragment row/col within 16-tile
  const int fk = (lane >> 4) * 8;    // fragment k offset

  f32x4 acc[4][4] = {};

  for (int k0 = 0; k0 < K; k0 += 32) {
    async16(gA + k0,                 lA);
    async16(gA + k0 + (size_t)16 * K, lA + 16 * 32);
    async16(gB + k0,                 lB);
    async16(gB + k0 + (size_t)16 * K, lB + 16 * 32);
    __syncthreads();   // compiler emits vmcnt(0) drain before barrier

    bf16x8 ar[4], br[4];
#pragma unroll
    for (int i = 0; i < 4; ++i) {
      ar[i] = *(const bf16x8*)(As + (wm + i * 16 + fr) * 32 + fk);
      br[i] = *(const bf16x8*)(Bs + (wn + i * 16 + fr) * 32 + fk);
    }
#pragma unroll
    for (int i = 0; i < 4; ++i)
#pragma unroll
      for (int j = 0; j < 4; ++j)
        acc[i][j] = __builtin_amdgcn_mfma_f32_16x16x32_bf16(ar[i], br[j], acc[i][j], 0, 0, 0);
    __syncthreads();
  }

  // epilogue: bias + optional relu, store bf16 or fp32
  const int crow = m0 + wm + (lane >> 4) * 4;
  const int ccol = n0 + wn + (lane & 15);
#pragma unroll
  for (int j = 0; j < 4; ++j) {
    float bv = bias[ccol + j * 16];
#pragma unroll
    for (int i = 0; i < 4; ++i) {
#pragma unroll
      for (int r = 0; r < 4; ++r) {
        float v = acc[i][j][r] + bv;
        if (RELU) v = fmaxf(v, 0.0f);
        size_t idx = (size_t)(crow + i * 16 + r) * N + ccol + j * 16;
        if (OUT_BF16) ((unsigned short*)Cout)[idx] = f2bf(v);
        else          ((float*)Cout)[idx] = v;
      }
    }
  }
}

// ---------------------------------------------------------------------------
// y_hat[r] = dot(feat_l[r], W3) + b3   (one wave per row)
// ---------------------------------------------------------------------------
__global__ __launch_bounds__(256) void yhat_kernel(
    const float* __restrict__ feat_l, const float* __restrict__ W3,
    const float* __restrict__ b3, float* __restrict__ out)
{
  int wave = threadIdx.x >> 6;
  int lane = threadIdx.x & 63;
  int row = blockIdx.x * 4 + wave;
  if (row >= SLAB) return;
  const float* f = feat_l + (size_t)row * HID2;
  float s = 0.f;
#pragma unroll
  for (int j = 0; j < HID2 / 64; ++j) s = fmaf(f[lane + j * 64], W3[lane + j * 64], s);
#pragma unroll
  for (int off = 32; off; off >>= 1) s += __shfl_down(s, off);
  if (lane == 0) out[row] = s + b3[0];
}

// ---------------------------------------------------------------------------
// feat_comb[r] = k[r]*feat_l[a[r]] + (1-k[r])*feat_l[b[r]]
// ---------------------------------------------------------------------------
__global__ __launch_bounds__(256) void comb_kernel(
    const float* __restrict__ feat_l, const int* __restrict__ ai,
    const int* __restrict__ bi, const float* __restrict__ kv,
    float* __restrict__ out)
{
  int row = blockIdx.x * 2 + (threadIdx.x >> 7);
  int c = (threadIdx.x & 127) << 2;
  float k = kv[row];
  float km1 = 1.0f - k;
  float4 fa = *(const float4*)(feat_l + (size_t)ai[row] * HID2 + c);
  float4 fb = *(const float4*)(feat_l + (size_t)bi[row] * HID2 + c);
  float4 o;
  o.x = k * fa.x + km1 * fb.x;
  o.y = k * fa.y + km1 * fb.y;
  o.z = k * fa.z + km1 * fb.z;
  o.w = k * fa.w + km1 * fb.w;
  *(float4*)(out + (size_t)row * HID2 + c) = o;
}

// ---------------------------------------------------------------------------
extern "C" void kernel_launch(void* const* d_in, const int* in_sizes, int n_in,
                              void* d_out, int out_size, void* d_ws, size_t ws_size,
                              hipStream_t stream)
{
  const float* X_l = (const float*)d_in[0];
  const float* y_l = (const float*)d_in[1];
  const float* X_u = (const float*)d_in[2];
  const float* y_u = (const float*)d_in[3];
  const float* W1  = (const float*)d_in[4];
  const float* b1  = (const float*)d_in[5];
  const float* W2  = (const float*)d_in[6];
  const float* b2  = (const float*)d_in[7];
  const float* W3  = (const float*)d_in[8];
  const float* b3  = (const float*)d_in[9];

  float* out_featu = (float*)d_out;
  float* out_comb  = out_featu + (size_t)SUNL * HID2;
  float* out_yhat  = out_comb + (size_t)SUNL * HID2;

  // Workspace (~174 MB): bf16 operands + bf16 hidden + fp32 feat_l + indices
  unsigned short* Xl_bf = (unsigned short*)d_ws;
  unsigned short* Xu_bf = Xl_bf + (size_t)SLAB * DIMX;
  unsigned short* W1T   = Xu_bf + (size_t)SUNL * DIMX;
  unsigned short* W2T   = W1T + (size_t)HID1 * DIMX;
  unsigned short* Hl_bf = W2T + (size_t)HID2 * HID1;
  unsigned short* Hu_bf = Hl_bf + (size_t)SLAB * HID1;
  float* feat_l = (float*)(Hu_bf + (size_t)SUNL * HID1);
  int*   ai = (int*)(feat_l + (size_t)SLAB * HID2);
  int*   bi = ai + SUNL;
  float* kv = (float*)(bi + SUNL);

  dim3 blk(256);
  dim3 tblk(32, 8);

  pairs_kernel<<<dim3(SUNL / 256), blk, 0, stream>>>(y_l, y_u, ai, bi, kv);

  // casts
  cast_bf16_kernel<<<dim3((SLAB * DIMX / 4) / 256), blk, 0, stream>>>(X_l, Xl_bf);
  cast_bf16_kernel<<<dim3((SUNL * DIMX / 4) / 256), blk, 0, stream>>>(X_u, Xu_bf);
  transpose_cast_kernel<<<dim3(HID1 / 32, DIMX / 32), tblk, 0, stream>>>(W1, W1T, DIMX, HID1);
  transpose_cast_kernel<<<dim3(HID2 / 32, HID1 / 32), tblk, 0, stream>>>(W2, W2T, HID1, HID2);

  // layer 1: H = relu(X @ W1 + b1) -> bf16
  gemm_bt_mfma<1, 1><<<dim3(HID1 / 128, SLAB / 128), blk, 0, stream>>>(
      Xl_bf, W1T, b1, Hl_bf, SLAB, HID1, DIMX);
  gemm_bt_mfma<1, 1><<<dim3(HID1 / 128, SUNL / 128), blk, 0, stream>>>(
      Xu_bf, W1T, b1, Hu_bf, SUNL, HID1, DIMX);

  // layer 2: feat = relu(H @ W2 + b2) -> fp32
  gemm_bt_mfma<0, 1><<<dim3(HID2 / 128, SLAB / 128), blk, 0, stream>>>(
      Hl_bf, W2T, b2, feat_l, SLAB, HID2, HID1);
  gemm_bt_mfma<0, 1><<<dim3(HID2 / 128, SUNL / 128), blk, 0, stream>>>(
      Hu_bf, W2T, b2, out_featu, SUNL, HID2, HID1);

  yhat_kernel<<<dim3(SLAB / 4), blk, 0, stream>>>(feat_l, W3, b3, out_yhat);
  comb_kernel<<<dim3(SUNL / 2), blk, 0, stream>>>(feat_l, ai, bi, kv, out_comb);
}

// Round 4
// 390.642 us; speedup vs baseline: 5.6931x; 1.1338x over previous
//
#include <hip/hip_runtime.h>
#include <stdint.h>

// Problem constants (match reference)
#define SLAB 8192    // SL
#define SUNL 16384   // SU
#define DIMX 1024
#define HID1 2048
#define HID2 512
#define KTRIES 8

typedef __attribute__((ext_vector_type(8))) short bf16x8;  // 8 bf16 = 4 VGPRs
typedef __attribute__((ext_vector_type(4))) float f32x4;

// fp32 -> bf16 round-to-nearest-even
__device__ __forceinline__ unsigned short f2bf(float f) {
  union { float f; uint32_t u; } c; c.f = f;
  return (unsigned short)((c.u + 0x7fffu + ((c.u >> 16) & 1u)) >> 16);
}

// async global->LDS, 16B per lane; lds dest = wave-uniform base + lane*16
__device__ __forceinline__ void async16(const void* g, void* l) {
  __builtin_amdgcn_global_load_lds(
      (const __attribute__((address_space(1))) unsigned int*)g,
      (__attribute__((address_space(3))) unsigned int*)l,
      16, 0, 0);
}

// ---------------------------------------------------------------------------
// Threefry2x32 (JAX-compatible, 20 rounds)
// ---------------------------------------------------------------------------
struct U2 { uint32_t x, y; };

__device__ __forceinline__ U2 threefry(uint32_t k0, uint32_t k1, uint32_t x0, uint32_t x1) {
  uint32_t ks2 = k0 ^ k1 ^ 0x1BD11BDAu;
  x0 += k0; x1 += k1;
#define TF_R(r) { x0 += x1; x1 = (x1 << (r)) | (x1 >> (32 - (r))); x1 ^= x0; }
  TF_R(13) TF_R(15) TF_R(26) TF_R(6)
  x0 += k1; x1 += ks2 + 1u;
  TF_R(17) TF_R(29) TF_R(16) TF_R(24)
  x0 += ks2; x1 += k0 + 2u;
  TF_R(13) TF_R(15) TF_R(26) TF_R(6)
  x0 += k0; x1 += k1 + 3u;
  TF_R(17) TF_R(29) TF_R(16) TF_R(24)
  x0 += k1; x1 += ks2 + 4u;
  TF_R(13) TF_R(15) TF_R(26) TF_R(6)
  x0 += ks2; x1 += k0 + 5u;
#undef TF_R
  return {x0, x1};
}

// Pair sampling — verified R1 (partitionable threefry; draw = bits1^bits2; &8191)
__global__ __launch_bounds__(256) void pairs_kernel(
    const float* __restrict__ y_l, const float* __restrict__ y_u,
    int* __restrict__ ai, int* __restrict__ bi, float* __restrict__ kv)
{
  int r = blockIdx.x * 256 + threadIdx.x;
  if (r >= SUNL) return;

  U2 ka  = threefry(0u, 42u, 0u, 0u);
  U2 kb  = threefry(0u, 42u, 0u, 1u);
  U2 k2a = threefry(ka.x, ka.y, 0u, 1u);
  U2 k2b = threefry(kb.x, kb.y, 0u, 1u);

  int iav[KTRIES], ibv[KTRIES];
#pragma unroll
  for (int c = 0; c < KTRIES; ++c) {
    uint32_t t = (uint32_t)(r * KTRIES + c);
    U2 oa = threefry(k2a.x, k2a.y, 0u, t);
    U2 ob = threefry(k2b.x, k2b.y, 0u, t);
    iav[c] = (int)((oa.x ^ oa.y) & (SLAB - 1));
    ibv[c] = (int)((ob.x ^ ob.y) & (SLAB - 1));
  }
  int a = iav[0], b = ibv[0];
#pragma unroll
  for (int c = 0; c < KTRIES; ++c) {
    if (iav[c] != ibv[c] && y_l[iav[c]] != y_l[ibv[c]]) { a = iav[c]; b = ibv[c]; break; }
  }
  float ya = y_l[a], yb = y_l[b];
  ai[r] = a; bi[r] = b; kv[r] = (y_u[r] - yb) / (ya - yb);
}

// ---------------------------------------------------------------------------
// cast fp32 -> bf16 for BOTH X_l and X_u in one launch (dest regions adjacent)
// ---------------------------------------------------------------------------
#define XL_BLOCKS (SLAB * DIMX / 4 / 256)   // 8192
__global__ __launch_bounds__(256) void cast_bf16_kernel(
    const float* __restrict__ Xl, const float* __restrict__ Xu,
    unsigned short* __restrict__ Xb)  // [SLAB+SUNL][DIMX] bf16
{
  size_t bi = blockIdx.x;
  const float* src; size_t i;
  if (bi < XL_BLOCKS) { src = Xl; i = bi * 256 + threadIdx.x; }
  else { src = Xu; i = (bi - XL_BLOCKS) * 256 + threadIdx.x; }
  float4 v = ((const float4*)src)[i];
  ushort4 o;
  o.x = f2bf(v.x); o.y = f2bf(v.y); o.z = f2bf(v.z); o.w = f2bf(v.w);
  size_t doff = (bi < XL_BLOCKS) ? 0 : (size_t)SLAB * DIMX / 4;
  ((ushort4*)Xb)[doff + i] = o;
}

// ---------------------------------------------------------------------------
// transpose + cast: W[K][N] fp32 -> WT[N][K] bf16. 32x32 LDS tile, block (32,8).
// ---------------------------------------------------------------------------
__global__ void transpose_cast_kernel(
    const float* __restrict__ W, unsigned short* __restrict__ WT, int K, int N)
{
  __shared__ float t[32][33];
  int k0 = blockIdx.y * 32, n0 = blockIdx.x * 32;
  int tx = threadIdx.x, ty = threadIdx.y;
#pragma unroll
  for (int i = 0; i < 32; i += 8)
    t[ty + i][tx] = W[(size_t)(k0 + ty + i) * N + n0 + tx];
  __syncthreads();
#pragma unroll
  for (int i = 0; i < 32; i += 8)
    WT[(size_t)(n0 + ty + i) * K + k0 + tx] = f2bf(t[tx][ty + i]);
}

// ---------------------------------------------------------------------------
// bf16 MFMA GEMM (m97 structure + k-chunk rotation swizzle):
//   C[M][N] = act(A[M][K] @ Bt[N][K]^T + bias)
// 128x128 tile, BK=32, 4 waves (2x2), each wave 64x64 = 4x4 16x16x32 MFMAs.
//
// LDS swizzle: row r's four 16B k-chunks are stored rotated by (r>>1)&3.
//   Staged by fetching global chunk ((slot - (r>>1))&3) into lane slot;
//   read back from slot ((q + (r>>1))&3), q = k-group = lane>>4.
//   Breaks the 8-way quarter-wave bank conflict (banks (r%2)*16 + q*4) into
//   2-way (free, m136). Rotation invariant mod 4 under +16-row second call.
//
// Output rows [0, Msplit) -> C0, rows [Msplit, M) -> C1 (tile-aligned split).
// ---------------------------------------------------------------------------
template<int OUT_BF16, int RELU>
__global__ __launch_bounds__(256) void gemm_bt_mfma(
    const unsigned short* __restrict__ A,   // [M][K] bf16
    const unsigned short* __restrict__ Bt,  // [N][K] bf16
    const float* __restrict__ bias,         // [N] fp32
    void* __restrict__ C0, void* __restrict__ C1, int Msplit,
    int M, int N, int K)
{
  __shared__ unsigned short As[128 * 32];   // 8 KB
  __shared__ unsigned short Bs[128 * 32];   // 8 KB

  const int tid  = threadIdx.x;
  const int wave = tid >> 6;
  const int lane = tid & 63;
  const int m0 = blockIdx.y * 128;
  const int n0 = blockIdx.x * 128;
  const int wm = (wave >> 1) * 64;
  const int wn = (wave & 1) * 64;

  // staging: lane covers row (wave*32 + lane/4), chunk slot (lane&3)
  const int srow  = wave * 32 + (lane >> 2);
  const int gchunk = ((lane & 3) - (srow >> 1)) & 3;   // rotation at fetch side
  const int scol  = gchunk * 8;                        // element offset in row
  const unsigned short* gA = A  + (size_t)(m0 + srow) * K + scol;
  const unsigned short* gB = Bt + (size_t)(n0 + srow) * K + scol;
  unsigned short* lA = As + wave * 32 * 32;            // wave-uniform LDS base
  unsigned short* lB = Bs + wave * 32 * 32;

  const int fr = lane & 15;          // fragment row/col within 16-tile
  const int q  = lane >> 4;          // k-group (k = q*8 + 0..7)

  f32x4 acc[4][4] = {};

  for (int k0 = 0; k0 < K; k0 += 32) {
    async16(gA + k0,                  lA);
    async16(gA + k0 + (size_t)16 * K, lA + 16 * 32);
    async16(gB + k0,                  lB);
    async16(gB + k0 + (size_t)16 * K, lB + 16 * 32);
    __syncthreads();

    bf16x8 ar[4], br[4];
#pragma unroll
    for (int i = 0; i < 4; ++i) {
      int rowA = wm + i * 16 + fr;
      int rowB = wn + i * 16 + fr;
      int slotA = ((q + (rowA >> 1)) & 3) * 8;   // un-rotate
      int slotB = ((q + (rowB >> 1)) & 3) * 8;
      ar[i] = *(const bf16x8*)(As + rowA * 32 + slotA);
      br[i] = *(const bf16x8*)(Bs + rowB * 32 + slotB);
    }
#pragma unroll
    for (int i = 0; i < 4; ++i)
#pragma unroll
      for (int j = 0; j < 4; ++j)
        acc[i][j] = __builtin_amdgcn_mfma_f32_16x16x32_bf16(ar[i], br[j], acc[i][j], 0, 0, 0);
    __syncthreads();
  }

  // epilogue: bias + optional relu; per-block output select (tile-aligned)
  void* Cb = (m0 < Msplit) ? C0 : C1;
  const int mbase = (m0 < Msplit) ? m0 : (m0 - Msplit);
  const int crow = mbase + wm + (lane >> 4) * 4;
  const int ccol = n0 + wn + (lane & 15);
#pragma unroll
  for (int j = 0; j < 4; ++j) {
    float bv = bias[ccol + j * 16];
#pragma unroll
    for (int i = 0; i < 4; ++i) {
#pragma unroll
      for (int r = 0; r < 4; ++r) {
        float v = acc[i][j][r] + bv;
        if (RELU) v = fmaxf(v, 0.0f);
        size_t idx = (size_t)(crow + i * 16 + r) * N + ccol + j * 16;
        if (OUT_BF16) ((unsigned short*)Cb)[idx] = f2bf(v);
        else          ((float*)Cb)[idx] = v;
      }
    }
  }
}

// ---------------------------------------------------------------------------
// y_hat[r] = dot(feat_l[r], W3) + b3   (one wave per row)
// ---------------------------------------------------------------------------
__global__ __launch_bounds__(256) void yhat_kernel(
    const float* __restrict__ feat_l, const float* __restrict__ W3,
    const float* __restrict__ b3, float* __restrict__ out)
{
  int wave = threadIdx.x >> 6;
  int lane = threadIdx.x & 63;
  int row = blockIdx.x * 4 + wave;
  if (row >= SLAB) return;
  const float* f = feat_l + (size_t)row * HID2;
  float s = 0.f;
#pragma unroll
  for (int j = 0; j < HID2 / 64; ++j) s = fmaf(f[lane + j * 64], W3[lane + j * 64], s);
#pragma unroll
  for (int off = 32; off; off >>= 1) s += __shfl_down(s, off);
  if (lane == 0) out[row] = s + b3[0];
}

// ---------------------------------------------------------------------------
// feat_comb[r] = k[r]*feat_l[a[r]] + (1-k[r])*feat_l[b[r]]
// ---------------------------------------------------------------------------
__global__ __launch_bounds__(256) void comb_kernel(
    const float* __restrict__ feat_l, const int* __restrict__ ai,
    const int* __restrict__ bi, const float* __restrict__ kv,
    float* __restrict__ out)
{
  int row = blockIdx.x * 2 + (threadIdx.x >> 7);
  int c = (threadIdx.x & 127) << 2;
  float k = kv[row];
  float km1 = 1.0f - k;
  float4 fa = *(const float4*)(feat_l + (size_t)ai[row] * HID2 + c);
  float4 fb = *(const float4*)(feat_l + (size_t)bi[row] * HID2 + c);
  float4 o;
  o.x = k * fa.x + km1 * fb.x;
  o.y = k * fa.y + km1 * fb.y;
  o.z = k * fa.z + km1 * fb.z;
  o.w = k * fa.w + km1 * fb.w;
  *(float4*)(out + (size_t)row * HID2 + c) = o;
}

// ---------------------------------------------------------------------------
extern "C" void kernel_launch(void* const* d_in, const int* in_sizes, int n_in,
                              void* d_out, int out_size, void* d_ws, size_t ws_size,
                              hipStream_t stream)
{
  const float* X_l = (const float*)d_in[0];
  const float* y_l = (const float*)d_in[1];
  const float* X_u = (const float*)d_in[2];
  const float* y_u = (const float*)d_in[3];
  const float* W1  = (const float*)d_in[4];
  const float* b1  = (const float*)d_in[5];
  const float* W2  = (const float*)d_in[6];
  const float* b2  = (const float*)d_in[7];
  const float* W3  = (const float*)d_in[8];
  const float* b3  = (const float*)d_in[9];

  float* out_featu = (float*)d_out;
  float* out_comb  = out_featu + (size_t)SUNL * HID2;
  float* out_yhat  = out_comb + (size_t)SUNL * HID2;

  // Workspace (~174 MB): X_bf = [Xl|Xu] contig, H_bf = [Hl|Hu] contig
  unsigned short* X_bf  = (unsigned short*)d_ws;                 // [24576][1024]
  unsigned short* W1T   = X_bf + (size_t)(SLAB + SUNL) * DIMX;
  unsigned short* W2T   = W1T + (size_t)HID1 * DIMX;
  unsigned short* H_bf  = W2T + (size_t)HID2 * HID1;             // [24576][2048]
  float* feat_l = (float*)(H_bf + (size_t)(SLAB + SUNL) * HID1);
  int*   ai = (int*)(feat_l + (size_t)SLAB * HID2);
  int*   bi = ai + SUNL;
  float* kv = (float*)(bi + SUNL);

  const int MTOT = SLAB + SUNL;   // 24576

  dim3 blk(256);
  dim3 tblk(32, 8);

  pairs_kernel<<<dim3(SUNL / 256), blk, 0, stream>>>(y_l, y_u, ai, bi, kv);

  cast_bf16_kernel<<<dim3(MTOT * DIMX / 4 / 256), blk, 0, stream>>>(X_l, X_u, X_bf);
  transpose_cast_kernel<<<dim3(HID1 / 32, DIMX / 32), tblk, 0, stream>>>(W1, W1T, DIMX, HID1);
  transpose_cast_kernel<<<dim3(HID2 / 32, HID1 / 32), tblk, 0, stream>>>(W2, W2T, HID1, HID2);

  // layer 1 (merged l+u): H = relu(X @ W1 + b1) -> bf16  [grid 16x192]
  gemm_bt_mfma<1, 1><<<dim3(HID1 / 128, MTOT / 128), blk, 0, stream>>>(
      X_bf, W1T, b1, H_bf, H_bf, MTOT * 2 /*no split*/, MTOT, HID1, DIMX);

  // layer 2 (merged l+u): feat = relu(H @ W2 + b2) -> fp32, split dest [grid 4x192]
  gemm_bt_mfma<0, 1><<<dim3(HID2 / 128, MTOT / 128), blk, 0, stream>>>(
      H_bf, W2T, b2, feat_l, out_featu, SLAB, MTOT, HID2, HID1);

  yhat_kernel<<<dim3(SLAB / 4), blk, 0, stream>>>(feat_l, W3, b3, out_yhat);
  comb_kernel<<<dim3(SUNL / 2), blk, 0, stream>>>(feat_l, ai, bi, kv, out_comb);
}